// Round 1
// baseline (975.785 us; speedup 1.0000x reference)
//
#include <hip/hip_runtime.h>
#include <hip/hip_bf16.h>
#include <cstdint>
#include <cstddef>

// Problem constants
#define B_    4
#define N_    1024
#define CIN_  256
#define HW_   256      // H == W == 256
#define D_    512
#define INK_  2304     // CIN * PH * PW
#define BN_   4096     // B * N

typedef __attribute__((ext_vector_type(8))) short bf16x8;
typedef __attribute__((ext_vector_type(4))) float f32x4;

__device__ __forceinline__ unsigned short f2bf(float f) {
    union { float f; unsigned u; } v; v.f = f;
    unsigned r = v.u + 0x7fffu + ((v.u >> 16) & 1u);   // round-to-nearest-even
    return (unsigned short)(r >> 16);
}

// ---------------------------------------------------------------------------
// Convert + transpose weights to bf16, K-contiguous ("TN" layout for MFMA).
// W1 (2304,512) -> W1t (512,2304); W2 (512,512) -> W2t (512,512).
// Writes coalesced (k fastest), reads strided (L2 absorbs, W1 is 4.7 MB).
// ---------------------------------------------------------------------------
__global__ __launch_bounds__(256) void k_convert(
    const float* __restrict__ W1, const float* __restrict__ W2,
    unsigned short* __restrict__ W1t, unsigned short* __restrict__ W2t)
{
    int i = blockIdx.x * 256 + threadIdx.x;
    const int n1 = INK_ * D_;
    if (i < n1) {
        int n = i / INK_, k = i % INK_;
        W1t[i] = f2bf(W1[(size_t)k * D_ + n]);
    } else {
        int j = i - n1;
        if (j < D_ * D_) {
            int n = j / D_, k = j % D_;
            W2t[j] = f2bf(W2[(size_t)k * D_ + n]);
        }
    }
}

// ---------------------------------------------------------------------------
// ROI-align gather. One block per box (4096 blocks), 256 threads = 256 chans.
// Sample metadata (36 samples: 4 offsets + 4 weights) built once in LDS.
// Output: flat bf16 (BN, 2304), element index c*9 + ph*3 + pw.
// ---------------------------------------------------------------------------
__global__ __launch_bounds__(256) void k_roi(
    const float* __restrict__ feats, const float* __restrict__ boxes,
    unsigned short* __restrict__ flat)
{
    __shared__ int   so[36][4];
    __shared__ float sw[36][4];
    const int bn = blockIdx.x;
    const int b  = bn >> 10;
    const int t  = threadIdx.x;

    if (t < 36) {
        const float* bx = boxes + (size_t)bn * 8;
        float xa = bx[0], xb = bx[2], xc = bx[4], xd = bx[6];
        float ya = bx[1], yb = bx[3], yc = bx[5], yd = bx[7];
        float xmn = fminf(fminf(xa, xb), fminf(xc, xd));
        float xmx = fmaxf(fmaxf(xa, xb), fmaxf(xc, xd));
        float ymn = fminf(fminf(ya, yb), fminf(yc, yd));
        float ymx = fmaxf(fmaxf(ya, yb), fmaxf(yc, yd));
        float sx1 = xmn * 0.25f, sy1 = ymn * 0.25f;
        float sx2 = xmx * 0.25f, sy2 = ymx * 0.25f;
        float rw = fmaxf(sx2 - sx1, 1.0f), rh = fmaxf(sy2 - sy1, 1.0f);
        float binw = rw * (1.0f / 3.0f), binh = rh * (1.0f / 3.0f);
        int row = t / 6, col = t % 6;                 // 6x6 grid, row-major
        float y = sy1 + (row * 0.5f + 0.25f) * binh;
        float x = sx1 + (col * 0.5f + 0.25f) * binw;
        float valid = (y > -1.0f && y < 256.0f && x > -1.0f && x < 256.0f) ? 1.0f : 0.0f;
        y = fminf(fmaxf(y, 0.0f), 255.0f);
        x = fminf(fmaxf(x, 0.0f), 255.0f);
        int y0 = (int)floorf(y), x0 = (int)floorf(x);
        int y1 = min(y0 + 1, 255), x1 = min(x0 + 1, 255);
        float ly = y - (float)y0, lx = x - (float)x0;
        float hy = 1.0f - ly, hx = 1.0f - lx;
        float m = 0.25f * valid;                      // fold 2x2-mean + valid
        so[t][0] = y0 * HW_ + x0;  so[t][1] = y0 * HW_ + x1;
        so[t][2] = y1 * HW_ + x0;  so[t][3] = y1 * HW_ + x1;
        sw[t][0] = hy * hx * m;    sw[t][1] = hy * lx * m;
        sw[t][2] = ly * hx * m;    sw[t][3] = ly * lx * m;
    }
    __syncthreads();

    const float* base = feats + ((size_t)(b * CIN_ + t) << 16);   // 256*256 plane
    float acc[9] = {0.f,0.f,0.f,0.f,0.f,0.f,0.f,0.f,0.f};
    #pragma unroll
    for (int j = 0; j < 36; ++j) {
        const int bin = ((j / 6) >> 1) * 3 + ((j % 6) >> 1);
        float v = sw[j][0] * base[so[j][0]] + sw[j][1] * base[so[j][1]]
                + sw[j][2] * base[so[j][2]] + sw[j][3] * base[so[j][3]];
        acc[bin] += v;
    }
    unsigned short* dst = flat + (size_t)bn * INK_ + t * 9;
    #pragma unroll
    for (int k = 0; k < 9; ++k) dst[k] = f2bf(acc[k]);
}

// ---------------------------------------------------------------------------
// bf16 MFMA GEMM, C = A(MxK) * Bt(NxK)^T + bias. Tile 64x64, BK=32.
// 256 threads = 4 waves; wave w does rows [w*16, w*16+16) x all 64 cols.
// LDS rows padded to 40 bf16 to avoid 8-way bank conflicts on ds_read_b128.
// RELU_BF16OUT: apply ReLU, store bf16; else store fp32.
// ---------------------------------------------------------------------------
template <int K, bool RELU_BF16OUT>
__global__ __launch_bounds__(256) void k_gemm(
    const unsigned short* __restrict__ A,
    const unsigned short* __restrict__ Bt,
    const float* __restrict__ bias,
    unsigned short* __restrict__ Cbf,
    float* __restrict__ Cf)
{
    __shared__ __align__(16) unsigned short Asl[64 * 40];
    __shared__ __align__(16) unsigned short Bsl[64 * 40];

    const int t  = threadIdx.x;
    const int m0 = blockIdx.x * 64;
    const int n0 = blockIdx.y * 64;
    const int w  = t >> 6;
    const int l  = t & 63;
    const int lane16 = l & 15;
    const int q  = l >> 4;

    f32x4 acc[4] = {};

    const int srow = t >> 2;       // 0..63
    const int sch  = t & 3;        // 0..3 : 8-elem chunk within BK=32
    const unsigned short* ga = A  + (size_t)(m0 + srow) * K + sch * 8;
    const unsigned short* gb = Bt + (size_t)(n0 + srow) * K + sch * 8;
    unsigned short* la = &Asl[srow * 40 + sch * 8];
    unsigned short* lb = &Bsl[srow * 40 + sch * 8];

    for (int k0 = 0; k0 < K; k0 += 32) {
        __syncthreads();
        *(bf16x8*)la = *(const bf16x8*)(ga + k0);
        *(bf16x8*)lb = *(const bf16x8*)(gb + k0);
        __syncthreads();
        bf16x8 af = *(const bf16x8*)&Asl[(w * 16 + lane16) * 40 + q * 8];
        #pragma unroll
        for (int nt = 0; nt < 4; ++nt) {
            bf16x8 bfv = *(const bf16x8*)&Bsl[(nt * 16 + lane16) * 40 + q * 8];
            acc[nt] = __builtin_amdgcn_mfma_f32_16x16x32_bf16(af, bfv, acc[nt], 0, 0, 0);
        }
    }

    #pragma unroll
    for (int nt = 0; nt < 4; ++nt) {
        int col = n0 + nt * 16 + lane16;
        float bs = bias[col];
        #pragma unroll
        for (int r = 0; r < 4; ++r) {
            int rowg = m0 + w * 16 + q * 4 + r;
            float v = acc[nt][r] + bs;
            if constexpr (RELU_BF16OUT) {
                v = fmaxf(v, 0.0f);
                Cbf[(size_t)rowg * D_ + col] = f2bf(v);
            } else {
                Cf[(size_t)rowg * D_ + col] = v;
            }
        }
    }
}

// ---------------------------------------------------------------------------
// Fused tail: pos matvec + LN1, add lines, LN2, transposed store.
// One block per (b,n) row; 256 threads, 2 elems each (d, d+256).
// ---------------------------------------------------------------------------
__device__ __forceinline__ void breduce2(float& a, float& b, float* red, int t) {
    #pragma unroll
    for (int off = 32; off > 0; off >>= 1) {
        a += __shfl_down(a, off);
        b += __shfl_down(b, off);
    }
    int w = t >> 6;
    if ((t & 63) == 0) { red[w] = a; red[4 + w] = b; }
    __syncthreads();
    a = red[0] + red[1] + red[2] + red[3];
    b = red[4] + red[5] + red[6] + red[7];
    __syncthreads();
}

__global__ __launch_bounds__(256) void k_tail(
    const float* __restrict__ lines, const float* __restrict__ boxes,
    const float* __restrict__ img_sizes,
    const float* __restrict__ Wb,  const float* __restrict__ bbv,
    const float* __restrict__ g1,  const float* __restrict__ be1,
    const float* __restrict__ g2,  const float* __restrict__ be2,
    float* __restrict__ out)
{
    __shared__ float red[8];
    const int row = blockIdx.x;
    const int b = row >> 10, n = row & 1023;
    const int t = threadIdx.x;

    const float* bx = boxes + (size_t)row * 8;
    float xmn = fminf(fminf(bx[0], bx[2]), fminf(bx[4], bx[6]));
    float xmx = fmaxf(fmaxf(bx[0], bx[2]), fmaxf(bx[4], bx[6]));
    float ymn = fminf(fminf(bx[1], bx[3]), fminf(bx[5], bx[7]));
    float ymx = fmaxf(fmaxf(bx[1], bx[3]), fmaxf(bx[5], bx[7]));
    float s0 = img_sizes[b * 2], s1 = img_sizes[b * 2 + 1];
    float q0 = xmn / s0, q1 = ymn / s1, q2 = xmx / s0, q3 = ymx / s1;

    float tv[2], sv[2];
    float sum = 0.f, sumsq = 0.f;
    #pragma unroll
    for (int i = 0; i < 2; ++i) {
        int d = t + i * 256;
        float v = q0 * Wb[d] + q1 * Wb[512 + d] + q2 * Wb[1024 + d] + q3 * Wb[1536 + d] + bbv[d];
        tv[i] = v; sum += v; sumsq += v * v;
    }
    breduce2(sum, sumsq, red, t);
    float mu = sum * (1.0f / 512.0f);
    float var = sumsq * (1.0f / 512.0f) - mu * mu;
    float rs = rsqrtf(var + 1e-5f);

    sum = 0.f; sumsq = 0.f;
    #pragma unroll
    for (int i = 0; i < 2; ++i) {
        int d = t + i * 256;
        float p = (tv[i] - mu) * rs * g1[d] + be1[d];
        float s = lines[(size_t)row * D_ + d] + p;
        sv[i] = s; sum += s; sumsq += s * s;
    }
    breduce2(sum, sumsq, red, t);
    float mu2 = sum * (1.0f / 512.0f);
    float var2 = sumsq * (1.0f / 512.0f) - mu2 * mu2;
    float rs2 = rsqrtf(var2 + 1e-5f);

    #pragma unroll
    for (int i = 0; i < 2; ++i) {
        int d = t + i * 256;
        float o = (sv[i] - mu2) * rs2 * g2[d] + be2[d];
        out[(size_t)b * (D_ * N_) + (size_t)d * N_ + n] = o;   // (B,D,R,C)
    }
}

__global__ __launch_bounds__(256) void k_mask(float* __restrict__ out) {
    int i = blockIdx.x * 256 + threadIdx.x;
    if (i < B_ * 32 * 32) out[(size_t)B_ * D_ * N_ + i] = 1.0f;
}

// ---------------------------------------------------------------------------
extern "C" void kernel_launch(void* const* d_in, const int* in_sizes, int n_in,
                              void* d_out, int out_size, void* d_ws, size_t ws_size,
                              hipStream_t stream)
{
    const float* feats = (const float*)d_in[0];
    const float* boxes = (const float*)d_in[1];
    const float* img   = (const float*)d_in[2];
    const float* W1    = (const float*)d_in[3];
    const float* b1    = (const float*)d_in[4];
    const float* W2    = (const float*)d_in[5];
    const float* b2    = (const float*)d_in[6];
    const float* Wb    = (const float*)d_in[7];
    const float* bbv   = (const float*)d_in[8];
    const float* g1    = (const float*)d_in[9];
    const float* be1   = (const float*)d_in[10];
    const float* g2    = (const float*)d_in[11];
    const float* be2   = (const float*)d_in[12];

    char* ws = (char*)d_ws;
    // ws layout (bytes):
    //   W1t  bf16 512x2304 : [0,          2,359,296)
    //   W2t  bf16 512x512  : [2,359,296,  2,883,584)
    //   flat bf16 4096x2304: [2,883,584, 21,757,952)
    //   act  bf16 4096x512 : [21,757,952, 25,952,256)
    //   lines f32 4096x512 : [25,952,256, 34,340,864)
    unsigned short* W1t  = (unsigned short*)(ws);
    unsigned short* W2t  = (unsigned short*)(ws + 2359296);
    unsigned short* flat = (unsigned short*)(ws + 2883584);
    unsigned short* act  = (unsigned short*)(ws + 21757952);
    float*          lines= (float*)(ws + 25952256);
    float*          out  = (float*)d_out;

    const int convTotal = INK_ * D_ + D_ * D_;
    k_convert<<<(convTotal + 255) / 256, 256, 0, stream>>>(W1, W2, W1t, W2t);

    k_roi<<<BN_, 256, 0, stream>>>(feats, boxes, flat);

    dim3 gg(64, 8);   // M/64 x N/64
    k_gemm<INK_, true ><<<gg, 256, 0, stream>>>(flat, W1t, b1, act, nullptr);
    k_gemm<D_,   false><<<gg, 256, 0, stream>>>(act,  W2t, b2, nullptr, lines);

    k_tail<<<BN_, 256, 0, stream>>>(lines, boxes, img, Wb, bbv, g1, be1, g2, be2, out);
    k_mask<<<16, 256, 0, stream>>>(out);
}

// Round 2
// 510.561 us; speedup vs baseline: 1.9112x; 1.9112x over previous
//
#include <hip/hip_runtime.h>
#include <hip/hip_bf16.h>
#include <cstdint>
#include <cstddef>

// Problem constants
#define B_    4
#define N_    1024
#define CIN_  256
#define HW_   256      // H == W == 256
#define D_    512
#define INK_  2304     // CIN * PH * PW
#define BN_   4096     // B * N

typedef __attribute__((ext_vector_type(8))) short bf16x8;
typedef __attribute__((ext_vector_type(4))) float f32x4;
typedef __attribute__((ext_vector_type(4))) unsigned short us4;

__device__ __forceinline__ unsigned short f2bf(float f) {
    union { float f; unsigned u; } v; v.f = f;
    unsigned r = v.u + 0x7fffu + ((v.u >> 16) & 1u);   // round-to-nearest-even
    return (unsigned short)(r >> 16);
}

// ---------------------------------------------------------------------------
// Generic 64x64 tiled transpose: src fp32 (Mrows, Ncols) -> dst (Ncols, Mrows)
// as OutT (ushort => bf16-convert, float => copy). Coalesced both directions.
// grid = (Ncols/64, Mrows/64, batches)
// ---------------------------------------------------------------------------
template <typename OutT>
__global__ __launch_bounds__(256) void k_t64(
    const float* __restrict__ src, OutT* __restrict__ dst,
    int Mrows, int Ncols, size_t sBatch, size_t dBatch)
{
    constexpr int PAD = (sizeof(OutT) == 2) ? 66 : 67;
    __shared__ OutT tile[64][PAD];
    const int n0 = blockIdx.x * 64;
    const int m0 = blockIdx.y * 64;
    const float* s = src + (size_t)blockIdx.z * sBatch;
    OutT* d = dst + (size_t)blockIdx.z * dBatch;
    const int t  = threadIdx.x;
    const int rr = t >> 4;          // 0..15
    const int cc = t & 15;          // 0..15

    #pragma unroll
    for (int i = 0; i < 4; ++i) {
        int row = i * 16 + rr;
        float4 v = *(const float4*)(s + (size_t)(m0 + row) * Ncols + n0 + cc * 4);
        if constexpr (sizeof(OutT) == 2) {
            tile[row][cc * 4 + 0] = f2bf(v.x);
            tile[row][cc * 4 + 1] = f2bf(v.y);
            tile[row][cc * 4 + 2] = f2bf(v.z);
            tile[row][cc * 4 + 3] = f2bf(v.w);
        } else {
            tile[row][cc * 4 + 0] = v.x;
            tile[row][cc * 4 + 1] = v.y;
            tile[row][cc * 4 + 2] = v.z;
            tile[row][cc * 4 + 3] = v.w;
        }
    }
    __syncthreads();
    #pragma unroll
    for (int i = 0; i < 4; ++i) {
        int p = i * 16 + rr;
        OutT v0 = tile[cc * 4 + 0][p];
        OutT v1 = tile[cc * 4 + 1][p];
        OutT v2 = tile[cc * 4 + 2][p];
        OutT v3 = tile[cc * 4 + 3][p];
        OutT* dp = d + (size_t)(n0 + p) * Mrows + m0 + cc * 4;
        if constexpr (sizeof(OutT) == 2) {
            *(us4*)dp = (us4){(unsigned short)v0, (unsigned short)v1,
                              (unsigned short)v2, (unsigned short)v3};
        } else {
            *(float4*)dp = make_float4(v0, v1, v2, v3);
        }
    }
}

// ---------------------------------------------------------------------------
// ROI-align gather from NHWC bf16 featsT (B, HW, CIN).
// Block = 2 boxes x 128 channel-pairs (256 threads). Wave-loads are 256 B
// contiguous (uint = 2 channels). Metadata (36 samples/box) in LDS.
// ---------------------------------------------------------------------------
__global__ __launch_bounds__(256) void k_roi2(
    const unsigned short* __restrict__ featsT, const float* __restrict__ boxes,
    unsigned short* __restrict__ flat)
{
    __shared__ int   so[2][36][4];
    __shared__ float sw[2][36][4];
    const int t = threadIdx.x;

    if (t < 72) {
        const int mbx = t / 36, s = t % 36;
        const int mbn = blockIdx.x * 2 + mbx;
        const float* bx = boxes + (size_t)mbn * 8;
        float xmn = fminf(fminf(bx[0], bx[2]), fminf(bx[4], bx[6]));
        float xmx = fmaxf(fmaxf(bx[0], bx[2]), fmaxf(bx[4], bx[6]));
        float ymn = fminf(fminf(bx[1], bx[3]), fminf(bx[5], bx[7]));
        float ymx = fmaxf(fmaxf(bx[1], bx[3]), fmaxf(bx[5], bx[7]));
        float sx1 = xmn * 0.25f, sy1 = ymn * 0.25f;
        float sx2 = xmx * 0.25f, sy2 = ymx * 0.25f;
        float rw = fmaxf(sx2 - sx1, 1.0f), rh = fmaxf(sy2 - sy1, 1.0f);
        float binw = rw * (1.0f / 3.0f), binh = rh * (1.0f / 3.0f);
        int row = s / 6, col = s % 6;
        float y = sy1 + (row * 0.5f + 0.25f) * binh;
        float x = sx1 + (col * 0.5f + 0.25f) * binw;
        float valid = (y > -1.0f && y < 256.0f && x > -1.0f && x < 256.0f) ? 1.0f : 0.0f;
        y = fminf(fmaxf(y, 0.0f), 255.0f);
        x = fminf(fmaxf(x, 0.0f), 255.0f);
        int y0 = (int)floorf(y), x0 = (int)floorf(x);
        int y1 = min(y0 + 1, 255), x1 = min(x0 + 1, 255);
        float ly = y - (float)y0, lx = x - (float)x0;
        float hy = 1.0f - ly, hx = 1.0f - lx;
        float m = 0.25f * valid;
        so[mbx][s][0] = y0 * HW_ + x0;  so[mbx][s][1] = y0 * HW_ + x1;
        so[mbx][s][2] = y1 * HW_ + x0;  so[mbx][s][3] = y1 * HW_ + x1;
        sw[mbx][s][0] = hy * hx * m;    sw[mbx][s][1] = hy * lx * m;
        sw[mbx][s][2] = ly * hx * m;    sw[mbx][s][3] = ly * lx * m;
    }
    __syncthreads();

    const int bxi = t >> 7;          // local box 0/1
    const int tid = t & 127;         // channel-pair
    const int bn  = blockIdx.x * 2 + bxi;
    const int b   = bn >> 10;
    const unsigned* basep = (const unsigned*)featsT + (size_t)b * (65536u * 128u) + tid;

    float a0[9] = {0,0,0,0,0,0,0,0,0};
    float a1[9] = {0,0,0,0,0,0,0,0,0};
    #pragma unroll
    for (int j = 0; j < 36; ++j) {
        const int bin = ((j / 6) >> 1) * 3 + ((j % 6) >> 1);
        int o0 = so[bxi][j][0], o1 = so[bxi][j][1], o2 = so[bxi][j][2], o3 = so[bxi][j][3];
        float w0 = sw[bxi][j][0], w1 = sw[bxi][j][1], w2 = sw[bxi][j][2], w3 = sw[bxi][j][3];
        unsigned u0 = basep[(size_t)o0 << 7];
        unsigned u1 = basep[(size_t)o1 << 7];
        unsigned u2 = basep[(size_t)o2 << 7];
        unsigned u3 = basep[(size_t)o3 << 7];
        float lo = w0 * __uint_as_float(u0 << 16) + w1 * __uint_as_float(u1 << 16)
                 + w2 * __uint_as_float(u2 << 16) + w3 * __uint_as_float(u3 << 16);
        float hi = w0 * __uint_as_float(u0 & 0xffff0000u) + w1 * __uint_as_float(u1 & 0xffff0000u)
                 + w2 * __uint_as_float(u2 & 0xffff0000u) + w3 * __uint_as_float(u3 & 0xffff0000u);
        a0[bin] += lo;
        a1[bin] += hi;
    }

    unsigned short tmp[18];
    #pragma unroll
    for (int k = 0; k < 9; ++k) { tmp[k] = f2bf(a0[k]); tmp[9 + k] = f2bf(a1[k]); }
    unsigned* dst = (unsigned*)(flat + (size_t)bn * INK_ + tid * 18);
    #pragma unroll
    for (int k = 0; k < 9; ++k) dst[k] = (unsigned)tmp[2 * k] | ((unsigned)tmp[2 * k + 1] << 16);
}

// ---------------------------------------------------------------------------
// FALLBACK path kernels (ws too small): round-1 NCHW gather + weight convert.
// ---------------------------------------------------------------------------
__global__ __launch_bounds__(256) void k_convert(
    const float* __restrict__ W1, const float* __restrict__ W2,
    unsigned short* __restrict__ W1t, unsigned short* __restrict__ W2t)
{
    int i = blockIdx.x * 256 + threadIdx.x;
    const int n1 = INK_ * D_;
    if (i < n1) {
        int n = i / INK_, k = i % INK_;
        W1t[i] = f2bf(W1[(size_t)k * D_ + n]);
    } else {
        int j = i - n1;
        if (j < D_ * D_) {
            int n = j / D_, k = j % D_;
            W2t[j] = f2bf(W2[(size_t)k * D_ + n]);
        }
    }
}

__global__ __launch_bounds__(256) void k_roi(
    const float* __restrict__ feats, const float* __restrict__ boxes,
    unsigned short* __restrict__ flat)
{
    __shared__ int   so[36][4];
    __shared__ float sw[36][4];
    const int bn = blockIdx.x;
    const int b  = bn >> 10;
    const int t  = threadIdx.x;

    if (t < 36) {
        const float* bx = boxes + (size_t)bn * 8;
        float xmn = fminf(fminf(bx[0], bx[2]), fminf(bx[4], bx[6]));
        float xmx = fmaxf(fmaxf(bx[0], bx[2]), fmaxf(bx[4], bx[6]));
        float ymn = fminf(fminf(bx[1], bx[3]), fminf(bx[5], bx[7]));
        float ymx = fmaxf(fmaxf(bx[1], bx[3]), fmaxf(bx[5], bx[7]));
        float sx1 = xmn * 0.25f, sy1 = ymn * 0.25f;
        float sx2 = xmx * 0.25f, sy2 = ymx * 0.25f;
        float rw = fmaxf(sx2 - sx1, 1.0f), rh = fmaxf(sy2 - sy1, 1.0f);
        float binw = rw * (1.0f / 3.0f), binh = rh * (1.0f / 3.0f);
        int row = t / 6, col = t % 6;
        float y = sy1 + (row * 0.5f + 0.25f) * binh;
        float x = sx1 + (col * 0.5f + 0.25f) * binw;
        float valid = (y > -1.0f && y < 256.0f && x > -1.0f && x < 256.0f) ? 1.0f : 0.0f;
        y = fminf(fmaxf(y, 0.0f), 255.0f);
        x = fminf(fmaxf(x, 0.0f), 255.0f);
        int y0 = (int)floorf(y), x0 = (int)floorf(x);
        int y1 = min(y0 + 1, 255), x1 = min(x0 + 1, 255);
        float ly = y - (float)y0, lx = x - (float)x0;
        float hy = 1.0f - ly, hx = 1.0f - lx;
        float m = 0.25f * valid;
        so[t][0] = y0 * HW_ + x0;  so[t][1] = y0 * HW_ + x1;
        so[t][2] = y1 * HW_ + x0;  so[t][3] = y1 * HW_ + x1;
        sw[t][0] = hy * hx * m;    sw[t][1] = hy * lx * m;
        sw[t][2] = ly * hx * m;    sw[t][3] = ly * lx * m;
    }
    __syncthreads();

    const float* base = feats + ((size_t)(b * CIN_ + t) << 16);
    float acc[9] = {0.f,0.f,0.f,0.f,0.f,0.f,0.f,0.f,0.f};
    #pragma unroll
    for (int j = 0; j < 36; ++j) {
        const int bin = ((j / 6) >> 1) * 3 + ((j % 6) >> 1);
        float v = sw[j][0] * base[so[j][0]] + sw[j][1] * base[so[j][1]]
                + sw[j][2] * base[so[j][2]] + sw[j][3] * base[so[j][3]];
        acc[bin] += v;
    }
    unsigned short* dst = flat + (size_t)bn * INK_ + t * 9;
    #pragma unroll
    for (int k = 0; k < 9; ++k) dst[k] = f2bf(acc[k]);
}

// ---------------------------------------------------------------------------
// bf16 MFMA GEMM, C = A(MxK) * Bt(NxK)^T + bias. Tile 64x64, BK=32.
// ---------------------------------------------------------------------------
template <int K, bool RELU_BF16OUT>
__global__ __launch_bounds__(256) void k_gemm(
    const unsigned short* __restrict__ A,
    const unsigned short* __restrict__ Bt,
    const float* __restrict__ bias,
    unsigned short* __restrict__ Cbf,
    float* __restrict__ Cf)
{
    __shared__ __align__(16) unsigned short Asl[64 * 40];
    __shared__ __align__(16) unsigned short Bsl[64 * 40];

    const int t  = threadIdx.x;
    const int m0 = blockIdx.x * 64;
    const int n0 = blockIdx.y * 64;
    const int w  = t >> 6;
    const int l  = t & 63;
    const int lane16 = l & 15;
    const int q  = l >> 4;

    f32x4 acc[4] = {};

    const int srow = t >> 2;
    const int sch  = t & 3;
    const unsigned short* ga = A  + (size_t)(m0 + srow) * K + sch * 8;
    const unsigned short* gb = Bt + (size_t)(n0 + srow) * K + sch * 8;
    unsigned short* la = &Asl[srow * 40 + sch * 8];
    unsigned short* lb = &Bsl[srow * 40 + sch * 8];

    for (int k0 = 0; k0 < K; k0 += 32) {
        __syncthreads();
        *(bf16x8*)la = *(const bf16x8*)(ga + k0);
        *(bf16x8*)lb = *(const bf16x8*)(gb + k0);
        __syncthreads();
        bf16x8 af = *(const bf16x8*)&Asl[(w * 16 + lane16) * 40 + q * 8];
        #pragma unroll
        for (int nt = 0; nt < 4; ++nt) {
            bf16x8 bfv = *(const bf16x8*)&Bsl[(nt * 16 + lane16) * 40 + q * 8];
            acc[nt] = __builtin_amdgcn_mfma_f32_16x16x32_bf16(af, bfv, acc[nt], 0, 0, 0);
        }
    }

    #pragma unroll
    for (int nt = 0; nt < 4; ++nt) {
        int col = n0 + nt * 16 + lane16;
        float bs = bias[col];
        #pragma unroll
        for (int r = 0; r < 4; ++r) {
            int rowg = m0 + w * 16 + q * 4 + r;
            float v = acc[nt][r] + bs;
            if constexpr (RELU_BF16OUT) {
                v = fmaxf(v, 0.0f);
                Cbf[(size_t)rowg * D_ + col] = f2bf(v);
            } else {
                Cf[(size_t)rowg * D_ + col] = v;
            }
        }
    }
}

// ---------------------------------------------------------------------------
// Fused tail: pos matvec + LN1, add lines, LN2.
// DIRECT=true: transposed store straight to out; else coalesced to outrow.
// ---------------------------------------------------------------------------
__device__ __forceinline__ void breduce2(float& a, float& b, float* red, int t) {
    #pragma unroll
    for (int off = 32; off > 0; off >>= 1) {
        a += __shfl_down(a, off);
        b += __shfl_down(b, off);
    }
    int w = t >> 6;
    if ((t & 63) == 0) { red[w] = a; red[4 + w] = b; }
    __syncthreads();
    a = red[0] + red[1] + red[2] + red[3];
    b = red[4] + red[5] + red[6] + red[7];
    __syncthreads();
}

template <bool DIRECT>
__global__ __launch_bounds__(256) void k_tail(
    const float* __restrict__ lines, const float* __restrict__ boxes,
    const float* __restrict__ img_sizes,
    const float* __restrict__ Wb,  const float* __restrict__ bbv,
    const float* __restrict__ g1,  const float* __restrict__ be1,
    const float* __restrict__ g2,  const float* __restrict__ be2,
    float* __restrict__ out)
{
    __shared__ float red[8];
    const int row = blockIdx.x;
    const int b = row >> 10, n = row & 1023;
    const int t = threadIdx.x;

    const float* bx = boxes + (size_t)row * 8;
    float xmn = fminf(fminf(bx[0], bx[2]), fminf(bx[4], bx[6]));
    float xmx = fmaxf(fmaxf(bx[0], bx[2]), fmaxf(bx[4], bx[6]));
    float ymn = fminf(fminf(bx[1], bx[3]), fminf(bx[5], bx[7]));
    float ymx = fmaxf(fmaxf(bx[1], bx[3]), fmaxf(bx[5], bx[7]));
    float s0 = img_sizes[b * 2], s1 = img_sizes[b * 2 + 1];
    float q0 = xmn / s0, q1 = ymn / s1, q2 = xmx / s0, q3 = ymx / s1;

    float tv[2], sv[2];
    float sum = 0.f, sumsq = 0.f;
    #pragma unroll
    for (int i = 0; i < 2; ++i) {
        int d = t + i * 256;
        float v = q0 * Wb[d] + q1 * Wb[512 + d] + q2 * Wb[1024 + d] + q3 * Wb[1536 + d] + bbv[d];
        tv[i] = v; sum += v; sumsq += v * v;
    }
    breduce2(sum, sumsq, red, t);
    float mu = sum * (1.0f / 512.0f);
    float var = sumsq * (1.0f / 512.0f) - mu * mu;
    float rs = rsqrtf(var + 1e-5f);

    sum = 0.f; sumsq = 0.f;
    #pragma unroll
    for (int i = 0; i < 2; ++i) {
        int d = t + i * 256;
        float p = (tv[i] - mu) * rs * g1[d] + be1[d];
        float s = lines[(size_t)row * D_ + d] + p;
        sv[i] = s; sum += s; sumsq += s * s;
    }
    breduce2(sum, sumsq, red, t);
    float mu2 = sum * (1.0f / 512.0f);
    float var2 = sumsq * (1.0f / 512.0f) - mu2 * mu2;
    float rs2 = rsqrtf(var2 + 1e-5f);

    #pragma unroll
    for (int i = 0; i < 2; ++i) {
        int d = t + i * 256;
        float o = (sv[i] - mu2) * rs2 * g2[d] + be2[d];
        if constexpr (DIRECT)
            out[(size_t)b * (D_ * N_) + (size_t)d * N_ + n] = o;
        else
            out[(size_t)row * D_ + d] = o;     // coalesced; transpose later
    }
}

__global__ __launch_bounds__(256) void k_mask(float* __restrict__ out) {
    int i = blockIdx.x * 256 + threadIdx.x;
    if (i < B_ * 32 * 32) out[(size_t)B_ * D_ * N_ + i] = 1.0f;
}

// ---------------------------------------------------------------------------
extern "C" void kernel_launch(void* const* d_in, const int* in_sizes, int n_in,
                              void* d_out, int out_size, void* d_ws, size_t ws_size,
                              hipStream_t stream)
{
    const float* feats = (const float*)d_in[0];
    const float* boxes = (const float*)d_in[1];
    const float* img   = (const float*)d_in[2];
    const float* W1    = (const float*)d_in[3];
    const float* b1    = (const float*)d_in[4];
    const float* W2    = (const float*)d_in[5];
    const float* b2    = (const float*)d_in[6];
    const float* Wb    = (const float*)d_in[7];
    const float* bbv   = (const float*)d_in[8];
    const float* g1    = (const float*)d_in[9];
    const float* be1   = (const float*)d_in[10];
    const float* g2    = (const float*)d_in[11];
    const float* be2   = (const float*)d_in[12];
    float* out = (float*)d_out;
    char* ws = (char*)d_ws;

    // Fast-path ws layout (bytes):
    const size_t OFF_FEATST = 0;                         // bf16 4x65536x256 = 134,217,728
    const size_t OFF_W1T    = 134217728;                 // bf16 512x2304   =   2,359,296
    const size_t OFF_W2T    = 136577024;                 // bf16 512x512    =     524,288
    const size_t OFF_FLAT   = 137101312;                 // bf16 4096x2304  =  18,874,368
    const size_t OFF_ACT    = 155975680;                 // bf16 4096x512   =   4,194,304
    const size_t OFF_LINES  = 160169984;                 // f32  4096x512   =   8,388,608
    const size_t OFF_OROW   = 168558592;                 // f32  4096x512   =   8,388,608
    const size_t NEED       = 176947200;

    if (ws_size >= NEED) {
        unsigned short* featsT = (unsigned short*)(ws + OFF_FEATST);
        unsigned short* W1t    = (unsigned short*)(ws + OFF_W1T);
        unsigned short* W2t    = (unsigned short*)(ws + OFF_W2T);
        unsigned short* flat   = (unsigned short*)(ws + OFF_FLAT);
        unsigned short* act    = (unsigned short*)(ws + OFF_ACT);
        float*          lines  = (float*)(ws + OFF_LINES);
        float*          orow   = (float*)(ws + OFF_OROW);

        // feats (B,CIN,HW) f32 -> featsT (B,HW,CIN) bf16
        k_t64<unsigned short><<<dim3(HW_*HW_/64, CIN_/64, B_), 256, 0, stream>>>(
            feats, featsT, CIN_, HW_*HW_, (size_t)CIN_*HW_*HW_, (size_t)CIN_*HW_*HW_);
        // W1 (2304,512) -> W1t (512,2304) bf16 ; W2 (512,512) -> W2t
        k_t64<unsigned short><<<dim3(D_/64, INK_/64, 1), 256, 0, stream>>>(
            W1, W1t, INK_, D_, 0, 0);
        k_t64<unsigned short><<<dim3(D_/64, D_/64, 1), 256, 0, stream>>>(
            W2, W2t, D_, D_, 0, 0);

        k_roi2<<<BN_/2, 256, 0, stream>>>(featsT, boxes, flat);

        dim3 gg(64, 8);
        k_gemm<INK_, true ><<<gg, 256, 0, stream>>>(flat, W1t, b1, act, nullptr);
        k_gemm<D_,   false><<<gg, 256, 0, stream>>>(act,  W2t, b2, nullptr, lines);

        k_tail<false><<<BN_, 256, 0, stream>>>(lines, boxes, img, Wb, bbv, g1, be1, g2, be2, orow);
        // orow (B,N,D) -> out (B,D,N)
        k_t64<float><<<dim3(D_/64, N_/64, B_), 256, 0, stream>>>(
            orow, out, N_, D_, (size_t)N_*D_, (size_t)D_*N_);
        k_mask<<<16, 256, 0, stream>>>(out);
    } else {
        // Fallback: round-1 path (34,340,864 bytes of ws)
        unsigned short* W1t  = (unsigned short*)(ws);
        unsigned short* W2t  = (unsigned short*)(ws + 2359296);
        unsigned short* flat = (unsigned short*)(ws + 2883584);
        unsigned short* act  = (unsigned short*)(ws + 21757952);
        float*          lines= (float*)(ws + 25952256);

        const int convTotal = INK_ * D_ + D_ * D_;
        k_convert<<<(convTotal + 255) / 256, 256, 0, stream>>>(W1, W2, W1t, W2t);
        k_roi<<<BN_, 256, 0, stream>>>(feats, boxes, flat);
        dim3 gg(64, 8);
        k_gemm<INK_, true ><<<gg, 256, 0, stream>>>(flat, W1t, b1, act, nullptr);
        k_gemm<D_,   false><<<gg, 256, 0, stream>>>(act,  W2t, b2, nullptr, lines);
        k_tail<true><<<BN_, 256, 0, stream>>>(lines, boxes, img, Wb, bbv, g1, be1, g2, be2, out);
        k_mask<<<16, 256, 0, stream>>>(out);
    }
}

// Round 3
// 506.400 us; speedup vs baseline: 1.9269x; 1.0082x over previous
//
#include <hip/hip_runtime.h>
#include <hip/hip_bf16.h>
#include <cstdint>
#include <cstddef>

// Problem constants
#define B_    4
#define N_    1024
#define CIN_  256
#define HW_   256      // H == W == 256
#define D_    512
#define INK_  2304     // CIN * PH * PW
#define BN_   4096     // B * N

typedef __attribute__((ext_vector_type(8))) short bf16x8;
typedef __attribute__((ext_vector_type(4))) float f32x4;
typedef __attribute__((ext_vector_type(4))) unsigned short us4;

#define AS1(p) ((const __attribute__((address_space(1))) void*)(p))
#define AS3(p) ((__attribute__((address_space(3))) void*)(p))

__device__ __forceinline__ unsigned short f2bf(float f) {
    union { float f; unsigned u; } v; v.f = f;
    unsigned r = v.u + 0x7fffu + ((v.u >> 16) & 1u);   // round-to-nearest-even
    return (unsigned short)(r >> 16);
}

// ---------------------------------------------------------------------------
// Generic 64x64 tiled transpose: src fp32 (Mrows, Ncols) -> dst (Ncols, Mrows)
// as OutT (ushort => bf16-convert, float => copy). Coalesced both directions.
// ---------------------------------------------------------------------------
template <typename OutT>
__global__ __launch_bounds__(256) void k_t64(
    const float* __restrict__ src, OutT* __restrict__ dst,
    int Mrows, int Ncols, size_t sBatch, size_t dBatch)
{
    constexpr int PAD = (sizeof(OutT) == 2) ? 66 : 67;
    __shared__ OutT tile[64][PAD];
    const int n0 = blockIdx.x * 64;
    const int m0 = blockIdx.y * 64;
    const float* s = src + (size_t)blockIdx.z * sBatch;
    OutT* d = dst + (size_t)blockIdx.z * dBatch;
    const int t  = threadIdx.x;
    const int rr = t >> 4;          // 0..15
    const int cc = t & 15;          // 0..15

    #pragma unroll
    for (int i = 0; i < 4; ++i) {
        int row = i * 16 + rr;
        float4 v = *(const float4*)(s + (size_t)(m0 + row) * Ncols + n0 + cc * 4);
        if constexpr (sizeof(OutT) == 2) {
            tile[row][cc * 4 + 0] = f2bf(v.x);
            tile[row][cc * 4 + 1] = f2bf(v.y);
            tile[row][cc * 4 + 2] = f2bf(v.z);
            tile[row][cc * 4 + 3] = f2bf(v.w);
        } else {
            tile[row][cc * 4 + 0] = v.x;
            tile[row][cc * 4 + 1] = v.y;
            tile[row][cc * 4 + 2] = v.z;
            tile[row][cc * 4 + 3] = v.w;
        }
    }
    __syncthreads();
    #pragma unroll
    for (int i = 0; i < 4; ++i) {
        int p = i * 16 + rr;
        OutT v0 = tile[cc * 4 + 0][p];
        OutT v1 = tile[cc * 4 + 1][p];
        OutT v2 = tile[cc * 4 + 2][p];
        OutT v3 = tile[cc * 4 + 3][p];
        OutT* dp = d + (size_t)(n0 + p) * Mrows + m0 + cc * 4;
        if constexpr (sizeof(OutT) == 2) {
            *(us4*)dp = (us4){(unsigned short)v0, (unsigned short)v1,
                              (unsigned short)v2, (unsigned short)v3};
        } else {
            *(float4*)dp = make_float4(v0, v1, v2, v3);
        }
    }
}

// ---------------------------------------------------------------------------
// ROI-align gather from NHWC bf16 featsT (B, HW, CIN).
// Block = 4 boxes x 64 channel-quads (256 threads). Each load is uint2 (8 B,
// 4 channels); a wave's 64 lanes cover 256 channels = 512 B contiguous.
// ---------------------------------------------------------------------------
__global__ __launch_bounds__(256) void k_roi3(
    const unsigned short* __restrict__ featsT, const float* __restrict__ boxes,
    unsigned short* __restrict__ flat)
{
    __shared__ int   so[4][36][4];
    __shared__ float sw[4][36][4];
    const int t = threadIdx.x;

    if (t < 144) {
        const int mbx = t / 36, s = t - mbx * 36;
        const int mbn = blockIdx.x * 4 + mbx;
        const float* bx = boxes + (size_t)mbn * 8;
        float xmn = fminf(fminf(bx[0], bx[2]), fminf(bx[4], bx[6]));
        float xmx = fmaxf(fmaxf(bx[0], bx[2]), fmaxf(bx[4], bx[6]));
        float ymn = fminf(fminf(bx[1], bx[3]), fminf(bx[5], bx[7]));
        float ymx = fmaxf(fmaxf(bx[1], bx[3]), fmaxf(bx[5], bx[7]));
        float sx1 = xmn * 0.25f, sy1 = ymn * 0.25f;
        float sx2 = xmx * 0.25f, sy2 = ymx * 0.25f;
        float rw = fmaxf(sx2 - sx1, 1.0f), rh = fmaxf(sy2 - sy1, 1.0f);
        float binw = rw * (1.0f / 3.0f), binh = rh * (1.0f / 3.0f);
        int row = s / 6, col = s % 6;
        float y = sy1 + (row * 0.5f + 0.25f) * binh;
        float x = sx1 + (col * 0.5f + 0.25f) * binw;
        float valid = (y > -1.0f && y < 256.0f && x > -1.0f && x < 256.0f) ? 1.0f : 0.0f;
        y = fminf(fmaxf(y, 0.0f), 255.0f);
        x = fminf(fmaxf(x, 0.0f), 255.0f);
        int y0 = (int)floorf(y), x0 = (int)floorf(x);
        int y1 = min(y0 + 1, 255), x1 = min(x0 + 1, 255);
        float ly = y - (float)y0, lx = x - (float)x0;
        float hy = 1.0f - ly, hx = 1.0f - lx;
        float m = 0.25f * valid;
        so[mbx][s][0] = y0 * HW_ + x0;  so[mbx][s][1] = y0 * HW_ + x1;
        so[mbx][s][2] = y1 * HW_ + x0;  so[mbx][s][3] = y1 * HW_ + x1;
        sw[mbx][s][0] = hy * hx * m;    sw[mbx][s][1] = hy * lx * m;
        sw[mbx][s][2] = ly * hx * m;    sw[mbx][s][3] = ly * lx * m;
    }
    __syncthreads();

    const int bxi = t >> 6;          // local box 0..3
    const int tid = t & 63;          // channel-quad
    const int bn  = blockIdx.x * 4 + bxi;
    const int b   = bn >> 10;
    const uint2* basep = (const uint2*)featsT + (size_t)b * (65536ull * 64ull) + tid;

    float a0[9] = {0,0,0,0,0,0,0,0,0};
    float a1[9] = {0,0,0,0,0,0,0,0,0};
    float a2[9] = {0,0,0,0,0,0,0,0,0};
    float a3[9] = {0,0,0,0,0,0,0,0,0};
    #pragma unroll
    for (int j = 0; j < 36; ++j) {
        const int bin = ((j / 6) >> 1) * 3 + ((j % 6) >> 1);
        #pragma unroll
        for (int p = 0; p < 4; ++p) {
            float wgt = sw[bxi][j][p];
            uint2 u = basep[(size_t)so[bxi][j][p] << 6];
            a0[bin] += wgt * __uint_as_float(u.x << 16);
            a1[bin] += wgt * __uint_as_float(u.x & 0xffff0000u);
            a2[bin] += wgt * __uint_as_float(u.y << 16);
            a3[bin] += wgt * __uint_as_float(u.y & 0xffff0000u);
        }
    }

    unsigned short tmp[36];
    #pragma unroll
    for (int k = 0; k < 9; ++k) {
        tmp[k] = f2bf(a0[k]); tmp[9 + k] = f2bf(a1[k]);
        tmp[18 + k] = f2bf(a2[k]); tmp[27 + k] = f2bf(a3[k]);
    }
    unsigned* dst = (unsigned*)(flat + (size_t)bn * INK_ + tid * 36);
    #pragma unroll
    for (int k = 0; k < 18; ++k)
        dst[k] = (unsigned)tmp[2 * k] | ((unsigned)tmp[2 * k + 1] << 16);
}

// ---------------------------------------------------------------------------
// m97-style bf16 MFMA GEMM: C = A(MxK) * Bt(NxK)^T + bias.
// Tile 128x64, BK=32, 256 threads (4 waves), global_load_lds staging,
// explicit LDS double-buffer, ONE barrier per K-step (grid = 1 block/CU,
// so prefetch-after-barrier is what hides the load latency).
// Wave w computes rows [w*32, w*32+32) x all 64 cols: 8 MFMA / 6 ds_read_b128.
// ---------------------------------------------------------------------------
template <int K, bool RELU_BF16OUT>
__global__ __launch_bounds__(256) void k_gemmB(
    const unsigned short* __restrict__ A,
    const unsigned short* __restrict__ Bt,
    const float* __restrict__ bias,
    unsigned short* __restrict__ Cbf,
    float* __restrict__ Cf)
{
    __shared__ __align__(16) unsigned short As[2][128 * 32];  // row stride 64 B
    __shared__ __align__(16) unsigned short Bs[2][64 * 32];

    const int t = threadIdx.x;
    const int w = t >> 6;
    const int lane = t & 63;
    const int lane16 = lane & 15;
    const int q = lane >> 4;
    const int m0 = blockIdx.x * 128;
    const int n0 = blockIdx.y * 64;

    // Staging: lane l of wave w deposits 16 B at LDS row (w*16 + l/4), chunk l%4.
    const int r4 = lane >> 2, c4 = lane & 3;
    const unsigned short* gA0 = A + (size_t)(m0 + w * 16 + r4) * K + c4 * 8;
    const unsigned short* gA1 = gA0 + (size_t)64 * K;
    const unsigned short* gB  = Bt + (size_t)(n0 + w * 16 + r4) * K + c4 * 8;

    f32x4 acc[2][4] = {};

    __builtin_amdgcn_global_load_lds(AS1(gA0), AS3(&As[0][(w * 16) * 32]), 16, 0, 0);
    __builtin_amdgcn_global_load_lds(AS1(gA1), AS3(&As[0][(64 + w * 16) * 32]), 16, 0, 0);
    __builtin_amdgcn_global_load_lds(AS1(gB ), AS3(&Bs[0][(w * 16) * 32]), 16, 0, 0);
    gA0 += 32; gA1 += 32; gB += 32;

    int cur = 0;
    for (int k0 = 0; k0 < K; k0 += 32) {
        __syncthreads();                    // buf[cur] ready (vmcnt drained)
        if (k0 + 32 < K) {                  // prefetch k+1 into buf[cur^1]
            __builtin_amdgcn_global_load_lds(AS1(gA0), AS3(&As[cur ^ 1][(w * 16) * 32]), 16, 0, 0);
            __builtin_amdgcn_global_load_lds(AS1(gA1), AS3(&As[cur ^ 1][(64 + w * 16) * 32]), 16, 0, 0);
            __builtin_amdgcn_global_load_lds(AS1(gB ), AS3(&Bs[cur ^ 1][(w * 16) * 32]), 16, 0, 0);
            gA0 += 32; gA1 += 32; gB += 32;
        }
        bf16x8 a0 = *(const bf16x8*)&As[cur][(w * 32 + lane16) * 32 + q * 8];
        bf16x8 a1 = *(const bf16x8*)&As[cur][(w * 32 + 16 + lane16) * 32 + q * 8];
        #pragma unroll
        for (int nt = 0; nt < 4; ++nt) {
            bf16x8 bv = *(const bf16x8*)&Bs[cur][(nt * 16 + lane16) * 32 + q * 8];
            acc[0][nt] = __builtin_amdgcn_mfma_f32_16x16x32_bf16(a0, bv, acc[0][nt], 0, 0, 0);
            acc[1][nt] = __builtin_amdgcn_mfma_f32_16x16x32_bf16(a1, bv, acc[1][nt], 0, 0, 0);
        }
        cur ^= 1;
    }

    #pragma unroll
    for (int nt = 0; nt < 4; ++nt) {
        int col = n0 + nt * 16 + lane16;
        float bs = bias[col];
        #pragma unroll
        for (int mg = 0; mg < 2; ++mg) {
            #pragma unroll
            for (int r = 0; r < 4; ++r) {
                int row = m0 + w * 32 + mg * 16 + q * 4 + r;
                float v = acc[mg][nt][r] + bs;
                if constexpr (RELU_BF16OUT) {
                    v = fmaxf(v, 0.0f);
                    Cbf[(size_t)row * D_ + col] = f2bf(v);
                } else {
                    Cf[(size_t)row * D_ + col] = v;
                }
            }
        }
    }
}

// ---------------------------------------------------------------------------
// FALLBACK path kernels (ws too small): round-1 NCHW gather + weight convert
// + 64x64 VGPR-staged GEMM.
// ---------------------------------------------------------------------------
__global__ __launch_bounds__(256) void k_convert(
    const float* __restrict__ W1, const float* __restrict__ W2,
    unsigned short* __restrict__ W1t, unsigned short* __restrict__ W2t)
{
    int i = blockIdx.x * 256 + threadIdx.x;
    const int n1 = INK_ * D_;
    if (i < n1) {
        int n = i / INK_, k = i % INK_;
        W1t[i] = f2bf(W1[(size_t)k * D_ + n]);
    } else {
        int j = i - n1;
        if (j < D_ * D_) {
            int n = j / D_, k = j % D_;
            W2t[j] = f2bf(W2[(size_t)k * D_ + n]);
        }
    }
}

__global__ __launch_bounds__(256) void k_roi(
    const float* __restrict__ feats, const float* __restrict__ boxes,
    unsigned short* __restrict__ flat)
{
    __shared__ int   so[36][4];
    __shared__ float sw[36][4];
    const int bn = blockIdx.x;
    const int b  = bn >> 10;
    const int t  = threadIdx.x;

    if (t < 36) {
        const float* bx = boxes + (size_t)bn * 8;
        float xmn = fminf(fminf(bx[0], bx[2]), fminf(bx[4], bx[6]));
        float xmx = fmaxf(fmaxf(bx[0], bx[2]), fmaxf(bx[4], bx[6]));
        float ymn = fminf(fminf(bx[1], bx[3]), fminf(bx[5], bx[7]));
        float ymx = fmaxf(fmaxf(bx[1], bx[3]), fmaxf(bx[5], bx[7]));
        float sx1 = xmn * 0.25f, sy1 = ymn * 0.25f;
        float sx2 = xmx * 0.25f, sy2 = ymx * 0.25f;
        float rw = fmaxf(sx2 - sx1, 1.0f), rh = fmaxf(sy2 - sy1, 1.0f);
        float binw = rw * (1.0f / 3.0f), binh = rh * (1.0f / 3.0f);
        int row = t / 6, col = t % 6;
        float y = sy1 + (row * 0.5f + 0.25f) * binh;
        float x = sx1 + (col * 0.5f + 0.25f) * binw;
        float valid = (y > -1.0f && y < 256.0f && x > -1.0f && x < 256.0f) ? 1.0f : 0.0f;
        y = fminf(fmaxf(y, 0.0f), 255.0f);
        x = fminf(fmaxf(x, 0.0f), 255.0f);
        int y0 = (int)floorf(y), x0 = (int)floorf(x);
        int y1 = min(y0 + 1, 255), x1 = min(x0 + 1, 255);
        float ly = y - (float)y0, lx = x - (float)x0;
        float hy = 1.0f - ly, hx = 1.0f - lx;
        float m = 0.25f * valid;
        so[t][0] = y0 * HW_ + x0;  so[t][1] = y0 * HW_ + x1;
        so[t][2] = y1 * HW_ + x0;  so[t][3] = y1 * HW_ + x1;
        sw[t][0] = hy * hx * m;    sw[t][1] = hy * lx * m;
        sw[t][2] = ly * hx * m;    sw[t][3] = ly * lx * m;
    }
    __syncthreads();

    const float* base = feats + ((size_t)(b * CIN_ + t) << 16);
    float acc[9] = {0.f,0.f,0.f,0.f,0.f,0.f,0.f,0.f,0.f};
    #pragma unroll
    for (int j = 0; j < 36; ++j) {
        const int bin = ((j / 6) >> 1) * 3 + ((j % 6) >> 1);
        float v = sw[j][0] * base[so[j][0]] + sw[j][1] * base[so[j][1]]
                + sw[j][2] * base[so[j][2]] + sw[j][3] * base[so[j][3]];
        acc[bin] += v;
    }
    unsigned short* dst = flat + (size_t)bn * INK_ + t * 9;
    #pragma unroll
    for (int k = 0; k < 9; ++k) dst[k] = f2bf(acc[k]);
}

template <int K, bool RELU_BF16OUT>
__global__ __launch_bounds__(256) void k_gemm(
    const unsigned short* __restrict__ A,
    const unsigned short* __restrict__ Bt,
    const float* __restrict__ bias,
    unsigned short* __restrict__ Cbf,
    float* __restrict__ Cf)
{
    __shared__ __align__(16) unsigned short Asl[64 * 40];
    __shared__ __align__(16) unsigned short Bsl[64 * 40];

    const int t  = threadIdx.x;
    const int m0 = blockIdx.x * 64;
    const int n0 = blockIdx.y * 64;
    const int w  = t >> 6;
    const int l  = t & 63;
    const int lane16 = l & 15;
    const int q  = l >> 4;

    f32x4 acc[4] = {};

    const int srow = t >> 2;
    const int sch  = t & 3;
    const unsigned short* ga = A  + (size_t)(m0 + srow) * K + sch * 8;
    const unsigned short* gb = Bt + (size_t)(n0 + srow) * K + sch * 8;
    unsigned short* la = &Asl[srow * 40 + sch * 8];
    unsigned short* lb = &Bsl[srow * 40 + sch * 8];

    for (int k0 = 0; k0 < K; k0 += 32) {
        __syncthreads();
        *(bf16x8*)la = *(const bf16x8*)(ga + k0);
        *(bf16x8*)lb = *(const bf16x8*)(gb + k0);
        __syncthreads();
        bf16x8 af = *(const bf16x8*)&Asl[(w * 16 + lane16) * 40 + q * 8];
        #pragma unroll
        for (int nt = 0; nt < 4; ++nt) {
            bf16x8 bfv = *(const bf16x8*)&Bsl[(nt * 16 + lane16) * 40 + q * 8];
            acc[nt] = __builtin_amdgcn_mfma_f32_16x16x32_bf16(af, bfv, acc[nt], 0, 0, 0);
        }
    }

    #pragma unroll
    for (int nt = 0; nt < 4; ++nt) {
        int col = n0 + nt * 16 + lane16;
        float bs = bias[col];
        #pragma unroll
        for (int r = 0; r < 4; ++r) {
            int rowg = m0 + w * 16 + q * 4 + r;
            float v = acc[nt][r] + bs;
            if constexpr (RELU_BF16OUT) {
                v = fmaxf(v, 0.0f);
                Cbf[(size_t)rowg * D_ + col] = f2bf(v);
            } else {
                Cf[(size_t)rowg * D_ + col] = v;
            }
        }
    }
}

// ---------------------------------------------------------------------------
// Fused tail: pos matvec + LN1, add lines, LN2.
// DIRECT=true: transposed store straight to out; else coalesced to outrow.
// ---------------------------------------------------------------------------
__device__ __forceinline__ void breduce2(float& a, float& b, float* red, int t) {
    #pragma unroll
    for (int off = 32; off > 0; off >>= 1) {
        a += __shfl_down(a, off);
        b += __shfl_down(b, off);
    }
    int w = t >> 6;
    if ((t & 63) == 0) { red[w] = a; red[4 + w] = b; }
    __syncthreads();
    a = red[0] + red[1] + red[2] + red[3];
    b = red[4] + red[5] + red[6] + red[7];
    __syncthreads();
}

template <bool DIRECT>
__global__ __launch_bounds__(256) void k_tail(
    const float* __restrict__ lines, const float* __restrict__ boxes,
    const float* __restrict__ img_sizes,
    const float* __restrict__ Wb,  const float* __restrict__ bbv,
    const float* __restrict__ g1,  const float* __restrict__ be1,
    const float* __restrict__ g2,  const float* __restrict__ be2,
    float* __restrict__ out)
{
    __shared__ float red[8];
    const int row = blockIdx.x;
    const int b = row >> 10, n = row & 1023;
    const int t = threadIdx.x;

    const float* bx = boxes + (size_t)row * 8;
    float xmn = fminf(fminf(bx[0], bx[2]), fminf(bx[4], bx[6]));
    float xmx = fmaxf(fmaxf(bx[0], bx[2]), fmaxf(bx[4], bx[6]));
    float ymn = fminf(fminf(bx[1], bx[3]), fminf(bx[5], bx[7]));
    float ymx = fmaxf(fmaxf(bx[1], bx[3]), fmaxf(bx[5], bx[7]));
    float s0 = img_sizes[b * 2], s1 = img_sizes[b * 2 + 1];
    float q0 = xmn / s0, q1 = ymn / s1, q2 = xmx / s0, q3 = ymx / s1;

    float tv[2], sv[2];
    float sum = 0.f, sumsq = 0.f;
    #pragma unroll
    for (int i = 0; i < 2; ++i) {
        int d = t + i * 256;
        float v = q0 * Wb[d] + q1 * Wb[512 + d] + q2 * Wb[1024 + d] + q3 * Wb[1536 + d] + bbv[d];
        tv[i] = v; sum += v; sumsq += v * v;
    }
    breduce2(sum, sumsq, red, t);
    float mu = sum * (1.0f / 512.0f);
    float var = sumsq * (1.0f / 512.0f) - mu * mu;
    float rs = rsqrtf(var + 1e-5f);

    sum = 0.f; sumsq = 0.f;
    #pragma unroll
    for (int i = 0; i < 2; ++i) {
        int d = t + i * 256;
        float p = (tv[i] - mu) * rs * g1[d] + be1[d];
        float s = lines[(size_t)row * D_ + d] + p;
        sv[i] = s; sum += s; sumsq += s * s;
    }
    breduce2(sum, sumsq, red, t);
    float mu2 = sum * (1.0f / 512.0f);
    float var2 = sumsq * (1.0f / 512.0f) - mu2 * mu2;
    float rs2 = rsqrtf(var2 + 1e-5f);

    #pragma unroll
    for (int i = 0; i < 2; ++i) {
        int d = t + i * 256;
        float o = (sv[i] - mu2) * rs2 * g2[d] + be2[d];
        if constexpr (DIRECT)
            out[(size_t)b * (D_ * N_) + (size_t)d * N_ + n] = o;
        else
            out[(size_t)row * D_ + d] = o;     // coalesced; transpose later
    }
}

__global__ __launch_bounds__(256) void k_mask(float* __restrict__ out) {
    int i = blockIdx.x * 256 + threadIdx.x;
    if (i < B_ * 32 * 32) out[(size_t)B_ * D_ * N_ + i] = 1.0f;
}

// ---------------------------------------------------------------------------
extern "C" void kernel_launch(void* const* d_in, const int* in_sizes, int n_in,
                              void* d_out, int out_size, void* d_ws, size_t ws_size,
                              hipStream_t stream)
{
    const float* feats = (const float*)d_in[0];
    const float* boxes = (const float*)d_in[1];
    const float* img   = (const float*)d_in[2];
    const float* W1    = (const float*)d_in[3];
    const float* b1    = (const float*)d_in[4];
    const float* W2    = (const float*)d_in[5];
    const float* b2    = (const float*)d_in[6];
    const float* Wb    = (const float*)d_in[7];
    const float* bbv   = (const float*)d_in[8];
    const float* g1    = (const float*)d_in[9];
    const float* be1   = (const float*)d_in[10];
    const float* g2    = (const float*)d_in[11];
    const float* be2   = (const float*)d_in[12];
    float* out = (float*)d_out;
    char* ws = (char*)d_ws;

    // Fast-path ws layout (bytes):
    const size_t OFF_FEATST = 0;                         // bf16 4x65536x256 = 134,217,728
    const size_t OFF_W1T    = 134217728;                 // bf16 512x2304   =   2,359,296
    const size_t OFF_W2T    = 136577024;                 // bf16 512x512    =     524,288
    const size_t OFF_FLAT   = 137101312;                 // bf16 4096x2304  =  18,874,368
    const size_t OFF_ACT    = 155975680;                 // bf16 4096x512   =   4,194,304
    const size_t OFF_LINES  = 160169984;                 // f32  4096x512   =   8,388,608
    const size_t OFF_OROW   = 168558592;                 // f32  4096x512   =   8,388,608
    const size_t NEED       = 176947200;

    if (ws_size >= NEED) {
        unsigned short* featsT = (unsigned short*)(ws + OFF_FEATST);
        unsigned short* W1t    = (unsigned short*)(ws + OFF_W1T);
        unsigned short* W2t    = (unsigned short*)(ws + OFF_W2T);
        unsigned short* flat   = (unsigned short*)(ws + OFF_FLAT);
        unsigned short* act    = (unsigned short*)(ws + OFF_ACT);
        float*          lines  = (float*)(ws + OFF_LINES);
        float*          orow   = (float*)(ws + OFF_OROW);

        // feats (B,CIN,HW) f32 -> featsT (B,HW,CIN) bf16
        k_t64<unsigned short><<<dim3(HW_*HW_/64, CIN_/64, B_), 256, 0, stream>>>(
            feats, featsT, CIN_, HW_*HW_, (size_t)CIN_*HW_*HW_, (size_t)CIN_*HW_*HW_);
        // W1 (2304,512) -> W1t (512,2304) bf16 ; W2 (512,512) -> W2t
        k_t64<unsigned short><<<dim3(D_/64, INK_/64, 1), 256, 0, stream>>>(
            W1, W1t, INK_, D_, 0, 0);
        k_t64<unsigned short><<<dim3(D_/64, D_/64, 1), 256, 0, stream>>>(
            W2, W2t, D_, D_, 0, 0);

        k_roi3<<<BN_/4, 256, 0, stream>>>(featsT, boxes, flat);

        dim3 gg(32, 8);   // M/128 x N/64 = 256 blocks
        k_gemmB<INK_, true ><<<gg, 256, 0, stream>>>(flat, W1t, b1, act, nullptr);
        k_gemmB<D_,   false><<<gg, 256, 0, stream>>>(act,  W2t, b2, nullptr, lines);

        k_tail<false><<<BN_, 256, 0, stream>>>(lines, boxes, img, Wb, bbv, g1, be1, g2, be2, orow);
        // orow (B,N,D) -> out (B,D,N)
        k_t64<float><<<dim3(D_/64, N_/64, B_), 256, 0, stream>>>(
            orow, out, N_, D_, (size_t)N_*D_, (size_t)D_*N_);
        k_mask<<<16, 256, 0, stream>>>(out);
    } else {
        // Fallback: round-1 path (34,340,864 bytes of ws)
        unsigned short* W1t  = (unsigned short*)(ws);
        unsigned short* W2t  = (unsigned short*)(ws + 2359296);
        unsigned short* flat = (unsigned short*)(ws + 2883584);
        unsigned short* act  = (unsigned short*)(ws + 21757952);
        float*          lines= (float*)(ws + 25952256);

        const int convTotal = INK_ * D_ + D_ * D_;
        k_convert<<<(convTotal + 255) / 256, 256, 0, stream>>>(W1, W2, W1t, W2t);
        k_roi<<<BN_, 256, 0, stream>>>(feats, boxes, flat);
        dim3 gg(64, 8);
        k_gemm<INK_, true ><<<gg, 256, 0, stream>>>(flat, W1t, b1, act, nullptr);
        k_gemm<D_,   false><<<gg, 256, 0, stream>>>(act,  W2t, b2, nullptr, lines);
        k_tail<true><<<BN_, 256, 0, stream>>>(lines, boxes, img, Wb, bbv, g1, be1, g2, be2, out);
        k_mask<<<16, 256, 0, stream>>>(out);
    }
}

// Round 4
// 506.300 us; speedup vs baseline: 1.9273x; 1.0002x over previous
//
#include <hip/hip_runtime.h>
#include <hip/hip_bf16.h>
#include <cstdint>
#include <cstddef>

// Problem constants
#define B_    4
#define N_    1024
#define CIN_  256
#define HW_   256      // H == W == 256
#define D_    512
#define INK_  2304     // CIN * PH * PW
#define BN_   4096     // B * N

typedef __attribute__((ext_vector_type(8))) short bf16x8;
typedef __attribute__((ext_vector_type(4))) float f32x4;
typedef __attribute__((ext_vector_type(4))) unsigned short us4;

#define AS1(p) ((const __attribute__((address_space(1))) void*)(p))
#define AS3(p) ((__attribute__((address_space(3))) void*)(p))

__device__ __forceinline__ unsigned short f2bf(float f) {
    union { float f; unsigned u; } v; v.f = f;
    unsigned r = v.u + 0x7fffu + ((v.u >> 16) & 1u);   // round-to-nearest-even
    return (unsigned short)(r >> 16);
}

// ---------------------------------------------------------------------------
// Generic 64x64 tiled transpose: src fp32 (Mrows, Ncols) -> dst (Ncols, Mrows)
// as OutT (ushort => bf16-convert, float => copy). Coalesced both directions.
// ---------------------------------------------------------------------------
template <typename OutT>
__global__ __launch_bounds__(256) void k_t64(
    const float* __restrict__ src, OutT* __restrict__ dst,
    int Mrows, int Ncols, size_t sBatch, size_t dBatch)
{
    constexpr int PAD = (sizeof(OutT) == 2) ? 66 : 67;
    __shared__ OutT tile[64][PAD];
    const int n0 = blockIdx.x * 64;
    const int m0 = blockIdx.y * 64;
    const float* s = src + (size_t)blockIdx.z * sBatch;
    OutT* d = dst + (size_t)blockIdx.z * dBatch;
    const int t  = threadIdx.x;
    const int rr = t >> 4;          // 0..15
    const int cc = t & 15;          // 0..15

    #pragma unroll
    for (int i = 0; i < 4; ++i) {
        int row = i * 16 + rr;
        float4 v = *(const float4*)(s + (size_t)(m0 + row) * Ncols + n0 + cc * 4);
        if constexpr (sizeof(OutT) == 2) {
            tile[row][cc * 4 + 0] = f2bf(v.x);
            tile[row][cc * 4 + 1] = f2bf(v.y);
            tile[row][cc * 4 + 2] = f2bf(v.z);
            tile[row][cc * 4 + 3] = f2bf(v.w);
        } else {
            tile[row][cc * 4 + 0] = v.x;
            tile[row][cc * 4 + 1] = v.y;
            tile[row][cc * 4 + 2] = v.z;
            tile[row][cc * 4 + 3] = v.w;
        }
    }
    __syncthreads();
    #pragma unroll
    for (int i = 0; i < 4; ++i) {
        int p = i * 16 + rr;
        OutT v0 = tile[cc * 4 + 0][p];
        OutT v1 = tile[cc * 4 + 1][p];
        OutT v2 = tile[cc * 4 + 2][p];
        OutT v3 = tile[cc * 4 + 3][p];
        OutT* dp = d + (size_t)(n0 + p) * Mrows + m0 + cc * 4;
        if constexpr (sizeof(OutT) == 2) {
            *(us4*)dp = (us4){(unsigned short)v0, (unsigned short)v1,
                              (unsigned short)v2, (unsigned short)v3};
        } else {
            *(float4*)dp = make_float4(v0, v1, v2, v3);
        }
    }
}

// ---------------------------------------------------------------------------
// ROI-align gather from NHWC bf16 featsT (B, HW, CIN).
// Block = 4 boxes x 64 channel-quads (256 threads). Each load is uint2 (8 B,
// 4 channels); a wave's 64 lanes cover 256 channels = 512 B contiguous.
// ---------------------------------------------------------------------------
__global__ __launch_bounds__(256) void k_roi3(
    const unsigned short* __restrict__ featsT, const float* __restrict__ boxes,
    unsigned short* __restrict__ flat)
{
    __shared__ int   so[4][36][4];
    __shared__ float sw[4][36][4];
    const int t = threadIdx.x;

    if (t < 144) {
        const int mbx = t / 36, s = t - mbx * 36;
        const int mbn = blockIdx.x * 4 + mbx;
        const float* bx = boxes + (size_t)mbn * 8;
        float xmn = fminf(fminf(bx[0], bx[2]), fminf(bx[4], bx[6]));
        float xmx = fmaxf(fmaxf(bx[0], bx[2]), fmaxf(bx[4], bx[6]));
        float ymn = fminf(fminf(bx[1], bx[3]), fminf(bx[5], bx[7]));
        float ymx = fmaxf(fmaxf(bx[1], bx[3]), fmaxf(bx[5], bx[7]));
        float sx1 = xmn * 0.25f, sy1 = ymn * 0.25f;
        float sx2 = xmx * 0.25f, sy2 = ymx * 0.25f;
        float rw = fmaxf(sx2 - sx1, 1.0f), rh = fmaxf(sy2 - sy1, 1.0f);
        float binw = rw * (1.0f / 3.0f), binh = rh * (1.0f / 3.0f);
        int row = s / 6, col = s % 6;
        float y = sy1 + (row * 0.5f + 0.25f) * binh;
        float x = sx1 + (col * 0.5f + 0.25f) * binw;
        float valid = (y > -1.0f && y < 256.0f && x > -1.0f && x < 256.0f) ? 1.0f : 0.0f;
        y = fminf(fmaxf(y, 0.0f), 255.0f);
        x = fminf(fmaxf(x, 0.0f), 255.0f);
        int y0 = (int)floorf(y), x0 = (int)floorf(x);
        int y1 = min(y0 + 1, 255), x1 = min(x0 + 1, 255);
        float ly = y - (float)y0, lx = x - (float)x0;
        float hy = 1.0f - ly, hx = 1.0f - lx;
        float m = 0.25f * valid;
        so[mbx][s][0] = y0 * HW_ + x0;  so[mbx][s][1] = y0 * HW_ + x1;
        so[mbx][s][2] = y1 * HW_ + x0;  so[mbx][s][3] = y1 * HW_ + x1;
        sw[mbx][s][0] = hy * hx * m;    sw[mbx][s][1] = hy * lx * m;
        sw[mbx][s][2] = ly * hx * m;    sw[mbx][s][3] = ly * lx * m;
    }
    __syncthreads();

    const int bxi = t >> 6;          // local box 0..3
    const int tid = t & 63;          // channel-quad
    const int bn  = blockIdx.x * 4 + bxi;
    const int b   = bn >> 10;
    const uint2* basep = (const uint2*)featsT + (size_t)b * (65536ull * 64ull) + tid;

    float a0[9] = {0,0,0,0,0,0,0,0,0};
    float a1[9] = {0,0,0,0,0,0,0,0,0};
    float a2[9] = {0,0,0,0,0,0,0,0,0};
    float a3[9] = {0,0,0,0,0,0,0,0,0};
    #pragma unroll
    for (int j = 0; j < 36; ++j) {
        const int bin = ((j / 6) >> 1) * 3 + ((j % 6) >> 1);
        #pragma unroll
        for (int p = 0; p < 4; ++p) {
            float wgt = sw[bxi][j][p];
            uint2 u = basep[(size_t)so[bxi][j][p] << 6];
            a0[bin] += wgt * __uint_as_float(u.x << 16);
            a1[bin] += wgt * __uint_as_float(u.x & 0xffff0000u);
            a2[bin] += wgt * __uint_as_float(u.y << 16);
            a3[bin] += wgt * __uint_as_float(u.y & 0xffff0000u);
        }
    }

    unsigned short tmp[36];
    #pragma unroll
    for (int k = 0; k < 9; ++k) {
        tmp[k] = f2bf(a0[k]); tmp[9 + k] = f2bf(a1[k]);
        tmp[18 + k] = f2bf(a2[k]); tmp[27 + k] = f2bf(a3[k]);
    }
    unsigned* dst = (unsigned*)(flat + (size_t)bn * INK_ + tid * 36);
    #pragma unroll
    for (int k = 0; k < 18; ++k)
        dst[k] = (unsigned)tmp[2 * k] | ((unsigned)tmp[2 * k + 1] << 16);
}

// ---------------------------------------------------------------------------
// GEMM1: m97-style bf16 MFMA, C = A(MxK) * Bt(NxK)^T + bias, ReLU, bf16 out.
// Tile 128x64, BK=32, global_load_lds staging, LDS double-buffer.
// ---------------------------------------------------------------------------
template <int K, bool RELU_BF16OUT>
__global__ __launch_bounds__(256) void k_gemmB(
    const unsigned short* __restrict__ A,
    const unsigned short* __restrict__ Bt,
    const float* __restrict__ bias,
    unsigned short* __restrict__ Cbf,
    float* __restrict__ Cf)
{
    __shared__ __align__(16) unsigned short As[2][128 * 32];  // row stride 64 B
    __shared__ __align__(16) unsigned short Bs[2][64 * 32];

    const int t = threadIdx.x;
    const int w = t >> 6;
    const int lane = t & 63;
    const int lane16 = lane & 15;
    const int q = lane >> 4;
    const int m0 = blockIdx.x * 128;
    const int n0 = blockIdx.y * 64;

    const int r4 = lane >> 2, c4 = lane & 3;
    const unsigned short* gA0 = A + (size_t)(m0 + w * 16 + r4) * K + c4 * 8;
    const unsigned short* gA1 = gA0 + (size_t)64 * K;
    const unsigned short* gB  = Bt + (size_t)(n0 + w * 16 + r4) * K + c4 * 8;

    f32x4 acc[2][4] = {};

    __builtin_amdgcn_global_load_lds(AS1(gA0), AS3(&As[0][(w * 16) * 32]), 16, 0, 0);
    __builtin_amdgcn_global_load_lds(AS1(gA1), AS3(&As[0][(64 + w * 16) * 32]), 16, 0, 0);
    __builtin_amdgcn_global_load_lds(AS1(gB ), AS3(&Bs[0][(w * 16) * 32]), 16, 0, 0);
    gA0 += 32; gA1 += 32; gB += 32;

    int cur = 0;
    for (int k0 = 0; k0 < K; k0 += 32) {
        __syncthreads();                    // buf[cur] ready (vmcnt drained)
        if (k0 + 32 < K) {                  // prefetch k+1 into buf[cur^1]
            __builtin_amdgcn_global_load_lds(AS1(gA0), AS3(&As[cur ^ 1][(w * 16) * 32]), 16, 0, 0);
            __builtin_amdgcn_global_load_lds(AS1(gA1), AS3(&As[cur ^ 1][(64 + w * 16) * 32]), 16, 0, 0);
            __builtin_amdgcn_global_load_lds(AS1(gB ), AS3(&Bs[cur ^ 1][(w * 16) * 32]), 16, 0, 0);
            gA0 += 32; gA1 += 32; gB += 32;
        }
        bf16x8 a0 = *(const bf16x8*)&As[cur][(w * 32 + lane16) * 32 + q * 8];
        bf16x8 a1 = *(const bf16x8*)&As[cur][(w * 32 + 16 + lane16) * 32 + q * 8];
        #pragma unroll
        for (int nt = 0; nt < 4; ++nt) {
            bf16x8 bv = *(const bf16x8*)&Bs[cur][(nt * 16 + lane16) * 32 + q * 8];
            acc[0][nt] = __builtin_amdgcn_mfma_f32_16x16x32_bf16(a0, bv, acc[0][nt], 0, 0, 0);
            acc[1][nt] = __builtin_amdgcn_mfma_f32_16x16x32_bf16(a1, bv, acc[1][nt], 0, 0, 0);
        }
        cur ^= 1;
    }

    #pragma unroll
    for (int nt = 0; nt < 4; ++nt) {
        int col = n0 + nt * 16 + lane16;
        float bs = bias[col];
        #pragma unroll
        for (int mg = 0; mg < 2; ++mg) {
            #pragma unroll
            for (int r = 0; r < 4; ++r) {
                int row = m0 + w * 32 + mg * 16 + q * 4 + r;
                float v = acc[mg][nt][r] + bs;
                if constexpr (RELU_BF16OUT) {
                    v = fmaxf(v, 0.0f);
                    Cbf[(size_t)row * D_ + col] = f2bf(v);
                } else {
                    Cf[(size_t)row * D_ + col] = v;
                }
            }
        }
    }
}

// ---------------------------------------------------------------------------
// Fused GEMM2 + bias + pos-matvec + LN1 + add + LN2 + transposed store + mask.
// Grid = 256 blocks x 256 threads. Block = 16 rows (boxes) x all 512 cols.
// W2t staged via double-buffered global_load_lds (LDS exactly 64 KB);
// A-fragments read directly from global (act is L2-hot, 4 MB).
// Epilogue: acc -> S2 (fp32, aliases dead Bs[0]) -> per-wave LN over 4 rows
// -> transposed 64 B-granular store to out(B,D,N). Mask folded in.
// ---------------------------------------------------------------------------
__global__ __launch_bounds__(256) void k_fuse2(
    const unsigned short* __restrict__ act,   // (4096,512) bf16
    const unsigned short* __restrict__ W2t,   // (512,512) bf16, row=n, K-contig
    const float* __restrict__ b2,
    const float* __restrict__ boxes,
    const float* __restrict__ img_sizes,
    const float* __restrict__ Wb,  const float* __restrict__ bbv,
    const float* __restrict__ g1,  const float* __restrict__ be1,
    const float* __restrict__ g2,  const float* __restrict__ be2,
    float* __restrict__ out)
{
    __shared__ __align__(16) unsigned short Bs[2][512 * 32];   // 2 x 32 KB
    float* S2 = (float*)&Bs[0][0];   // 16 x 512 fp32 = 32 KB, aliases Bs[0]

    const int t = threadIdx.x;
    const int w = t >> 6, l = t & 63;
    const int lane16 = l & 15, q = l >> 4;
    const int m0 = blockIdx.x * 16;
    const int b  = m0 >> 10;

    // B staging: thread t stages rows r = (t>>2) + 64*i, 16 B chunk c = t&3.
    // LDS offset = uniform(w,i) + l*16 B  (global_load_lds addressing rule).
    const unsigned short* gB = W2t + (size_t)(t >> 2) * D_ + (t & 3) * 8;
    #pragma unroll
    for (int i = 0; i < 8; ++i)
        __builtin_amdgcn_global_load_lds(AS1(gB + (size_t)i * 64 * D_),
            AS3(&Bs[0][(t >> 2) * 32 + (t & 3) * 8 + i * 2048]), 16, 0, 0);

    f32x4 acc[8] = {};
    const unsigned short* gA = act + (size_t)(m0 + lane16) * D_ + q * 8;

    int cur = 0;
    for (int k0 = 0; k0 < D_; k0 += 32) {
        __syncthreads();                       // Bs[cur] staged (vmcnt drained)
        bf16x8 av = *(const bf16x8*)(gA + k0); // A direct from global (L2-hot)
        if (k0 + 32 < D_) {
            #pragma unroll
            for (int i = 0; i < 8; ++i)
                __builtin_amdgcn_global_load_lds(AS1(gB + k0 + 32 + (size_t)i * 64 * D_),
                    AS3(&Bs[cur ^ 1][(t >> 2) * 32 + (t & 3) * 8 + i * 2048]), 16, 0, 0);
        }
        #pragma unroll
        for (int nt = 0; nt < 8; ++nt) {
            bf16x8 bv = *(const bf16x8*)&Bs[cur][(w * 128 + nt * 16 + lane16) * 32 + q * 8];
            acc[nt] = __builtin_amdgcn_mfma_f32_16x16x32_bf16(av, bv, acc[nt], 0, 0, 0);
        }
        cur ^= 1;
    }
    __syncthreads();   // all ds_reads done -> safe to overwrite Bs[0] via S2

    // acc -> S2 (+bias). C/D layout: row = q*4+r, col = lane16 (per n-tile).
    #pragma unroll
    for (int nt = 0; nt < 8; ++nt) {
        int col = w * 128 + nt * 16 + lane16;
        float bs = b2[col];
        #pragma unroll
        for (int r = 0; r < 4; ++r)
            S2[(q * 4 + r) * D_ + col] = acc[nt][r] + bs;
    }
    __syncthreads();

    // Per-wave LN pipeline: wave w owns rows w*4 .. w*4+4 (disjoint).
    const float si0 = img_sizes[b * 2], si1 = img_sizes[b * 2 + 1];
    #pragma unroll 1
    for (int j = 0; j < 4; ++j) {
        const int rho = w * 4 + j;
        const float* bx = boxes + (size_t)(m0 + rho) * 8;
        float xmn = fminf(fminf(bx[0], bx[2]), fminf(bx[4], bx[6]));
        float xmx = fmaxf(fmaxf(bx[0], bx[2]), fmaxf(bx[4], bx[6]));
        float ymn = fminf(fminf(bx[1], bx[3]), fminf(bx[5], bx[7]));
        float ymx = fmaxf(fmaxf(bx[1], bx[3]), fmaxf(bx[5], bx[7]));
        float q0 = xmn / si0, q1 = ymn / si1, q2 = xmx / si0, q3 = ymx / si1;

        float tp[8], su = 0.f, sq = 0.f;
        #pragma unroll
        for (int i = 0; i < 8; ++i) {
            int d = i * 64 + l;
            float v = q0 * Wb[d] + q1 * Wb[512 + d] + q2 * Wb[1024 + d]
                    + q3 * Wb[1536 + d] + bbv[d];
            tp[i] = v; su += v; sq += v * v;
        }
        #pragma unroll
        for (int off = 32; off > 0; off >>= 1) {
            su += __shfl_xor(su, off); sq += __shfl_xor(sq, off);
        }
        float mu = su * (1.0f / 512.0f);
        float rs = rsqrtf(sq * (1.0f / 512.0f) - mu * mu + 1e-5f);

        float sv[8]; su = 0.f; sq = 0.f;
        #pragma unroll
        for (int i = 0; i < 8; ++i) {
            int d = i * 64 + l;
            float p = (tp[i] - mu) * rs * g1[d] + be1[d];
            float s = S2[rho * D_ + d] + p;
            sv[i] = s; su += s; sq += s * s;
        }
        #pragma unroll
        for (int off = 32; off > 0; off >>= 1) {
            su += __shfl_xor(su, off); sq += __shfl_xor(sq, off);
        }
        float mu2 = su * (1.0f / 512.0f);
        float rs2 = rsqrtf(sq * (1.0f / 512.0f) - mu2 * mu2 + 1e-5f);

        #pragma unroll
        for (int i = 0; i < 8; ++i) {
            int d = i * 64 + l;
            S2[rho * D_ + d] = (sv[i] - mu2) * rs2 * g2[d] + be2[d];
        }
    }
    __syncthreads();

    // Transposed store: out[b][d][nb..nb+16). 4 lanes cover 64 B per d.
    const int nb = m0 & 1023;
    float* ob = out + (size_t)b * (D_ * N_) + nb;
    const int dd = t >> 2, part = t & 3;
    #pragma unroll
    for (int i = 0; i < 8; ++i) {
        int d = i * 64 + dd;
        float4 v;
        v.x = S2[(part * 4 + 0) * D_ + d];
        v.y = S2[(part * 4 + 1) * D_ + d];
        v.z = S2[(part * 4 + 2) * D_ + d];
        v.w = S2[(part * 4 + 3) * D_ + d];
        *(float4*)(ob + (size_t)d * N_ + part * 4) = v;
    }
    if (t < 16) out[(size_t)B_ * D_ * N_ + m0 + t] = 1.0f;   // masks
}

// ---------------------------------------------------------------------------
// FALLBACK path kernels (ws too small): round-1 NCHW gather + weight convert
// + 64x64 VGPR-staged GEMM + standalone tail/mask.
// ---------------------------------------------------------------------------
__global__ __launch_bounds__(256) void k_convert(
    const float* __restrict__ W1, const float* __restrict__ W2,
    unsigned short* __restrict__ W1t, unsigned short* __restrict__ W2t)
{
    int i = blockIdx.x * 256 + threadIdx.x;
    const int n1 = INK_ * D_;
    if (i < n1) {
        int n = i / INK_, k = i % INK_;
        W1t[i] = f2bf(W1[(size_t)k * D_ + n]);
    } else {
        int j = i - n1;
        if (j < D_ * D_) {
            int n = j / D_, k = j % D_;
            W2t[j] = f2bf(W2[(size_t)k * D_ + n]);
        }
    }
}

__global__ __launch_bounds__(256) void k_roi(
    const float* __restrict__ feats, const float* __restrict__ boxes,
    unsigned short* __restrict__ flat)
{
    __shared__ int   so[36][4];
    __shared__ float sw[36][4];
    const int bn = blockIdx.x;
    const int b  = bn >> 10;
    const int t  = threadIdx.x;

    if (t < 36) {
        const float* bx = boxes + (size_t)bn * 8;
        float xmn = fminf(fminf(bx[0], bx[2]), fminf(bx[4], bx[6]));
        float xmx = fmaxf(fmaxf(bx[0], bx[2]), fmaxf(bx[4], bx[6]));
        float ymn = fminf(fminf(bx[1], bx[3]), fminf(bx[5], bx[7]));
        float ymx = fmaxf(fmaxf(bx[1], bx[3]), fmaxf(bx[5], bx[7]));
        float sx1 = xmn * 0.25f, sy1 = ymn * 0.25f;
        float sx2 = xmx * 0.25f, sy2 = ymx * 0.25f;
        float rw = fmaxf(sx2 - sx1, 1.0f), rh = fmaxf(sy2 - sy1, 1.0f);
        float binw = rw * (1.0f / 3.0f), binh = rh * (1.0f / 3.0f);
        int row = t / 6, col = t % 6;
        float y = sy1 + (row * 0.5f + 0.25f) * binh;
        float x = sx1 + (col * 0.5f + 0.25f) * binw;
        float valid = (y > -1.0f && y < 256.0f && x > -1.0f && x < 256.0f) ? 1.0f : 0.0f;
        y = fminf(fmaxf(y, 0.0f), 255.0f);
        x = fminf(fmaxf(x, 0.0f), 255.0f);
        int y0 = (int)floorf(y), x0 = (int)floorf(x);
        int y1 = min(y0 + 1, 255), x1 = min(x0 + 1, 255);
        float ly = y - (float)y0, lx = x - (float)x0;
        float hy = 1.0f - ly, hx = 1.0f - lx;
        float m = 0.25f * valid;
        so[t][0] = y0 * HW_ + x0;  so[t][1] = y0 * HW_ + x1;
        so[t][2] = y1 * HW_ + x0;  so[t][3] = y1 * HW_ + x1;
        sw[t][0] = hy * hx * m;    sw[t][1] = hy * lx * m;
        sw[t][2] = ly * hx * m;    sw[t][3] = ly * lx * m;
    }
    __syncthreads();

    const float* base = feats + ((size_t)(b * CIN_ + t) << 16);
    float acc[9] = {0.f,0.f,0.f,0.f,0.f,0.f,0.f,0.f,0.f};
    #pragma unroll
    for (int j = 0; j < 36; ++j) {
        const int bin = ((j / 6) >> 1) * 3 + ((j % 6) >> 1);
        float v = sw[j][0] * base[so[j][0]] + sw[j][1] * base[so[j][1]]
                + sw[j][2] * base[so[j][2]] + sw[j][3] * base[so[j][3]];
        acc[bin] += v;
    }
    unsigned short* dst = flat + (size_t)bn * INK_ + t * 9;
    #pragma unroll
    for (int k = 0; k < 9; ++k) dst[k] = f2bf(acc[k]);
}

template <int K, bool RELU_BF16OUT>
__global__ __launch_bounds__(256) void k_gemm(
    const unsigned short* __restrict__ A,
    const unsigned short* __restrict__ Bt,
    const float* __restrict__ bias,
    unsigned short* __restrict__ Cbf,
    float* __restrict__ Cf)
{
    __shared__ __align__(16) unsigned short Asl[64 * 40];
    __shared__ __align__(16) unsigned short Bsl[64 * 40];

    const int t  = threadIdx.x;
    const int m0 = blockIdx.x * 64;
    const int n0 = blockIdx.y * 64;
    const int w  = t >> 6;
    const int l  = t & 63;
    const int lane16 = l & 15;
    const int q  = l >> 4;

    f32x4 acc[4] = {};

    const int srow = t >> 2;
    const int sch  = t & 3;
    const unsigned short* ga = A  + (size_t)(m0 + srow) * K + sch * 8;
    const unsigned short* gb = Bt + (size_t)(n0 + srow) * K + sch * 8;
    unsigned short* la = &Asl[srow * 40 + sch * 8];
    unsigned short* lb = &Bsl[srow * 40 + sch * 8];

    for (int k0 = 0; k0 < K; k0 += 32) {
        __syncthreads();
        *(bf16x8*)la = *(const bf16x8*)(ga + k0);
        *(bf16x8*)lb = *(const bf16x8*)(gb + k0);
        __syncthreads();
        bf16x8 af = *(const bf16x8*)&Asl[(w * 16 + lane16) * 40 + q * 8];
        #pragma unroll
        for (int nt = 0; nt < 4; ++nt) {
            bf16x8 bfv = *(const bf16x8*)&Bsl[(nt * 16 + lane16) * 40 + q * 8];
            acc[nt] = __builtin_amdgcn_mfma_f32_16x16x32_bf16(af, bfv, acc[nt], 0, 0, 0);
        }
    }

    #pragma unroll
    for (int nt = 0; nt < 4; ++nt) {
        int col = n0 + nt * 16 + lane16;
        float bs = bias[col];
        #pragma unroll
        for (int r = 0; r < 4; ++r) {
            int rowg = m0 + w * 16 + q * 4 + r;
            float v = acc[nt][r] + bs;
            if constexpr (RELU_BF16OUT) {
                v = fmaxf(v, 0.0f);
                Cbf[(size_t)rowg * D_ + col] = f2bf(v);
            } else {
                Cf[(size_t)rowg * D_ + col] = v;
            }
        }
    }
}

__device__ __forceinline__ void breduce2(float& a, float& b, float* red, int t) {
    #pragma unroll
    for (int off = 32; off > 0; off >>= 1) {
        a += __shfl_down(a, off);
        b += __shfl_down(b, off);
    }
    int w = t >> 6;
    if ((t & 63) == 0) { red[w] = a; red[4 + w] = b; }
    __syncthreads();
    a = red[0] + red[1] + red[2] + red[3];
    b = red[4] + red[5] + red[6] + red[7];
    __syncthreads();
}

__global__ __launch_bounds__(256) void k_tail(
    const float* __restrict__ lines, const float* __restrict__ boxes,
    const float* __restrict__ img_sizes,
    const float* __restrict__ Wb,  const float* __restrict__ bbv,
    const float* __restrict__ g1,  const float* __restrict__ be1,
    const float* __restrict__ g2,  const float* __restrict__ be2,
    float* __restrict__ out)
{
    __shared__ float red[8];
    const int row = blockIdx.x;
    const int b = row >> 10, n = row & 1023;
    const int t = threadIdx.x;

    const float* bx = boxes + (size_t)row * 8;
    float xmn = fminf(fminf(bx[0], bx[2]), fminf(bx[4], bx[6]));
    float xmx = fmaxf(fmaxf(bx[0], bx[2]), fmaxf(bx[4], bx[6]));
    float ymn = fminf(fminf(bx[1], bx[3]), fminf(bx[5], bx[7]));
    float ymx = fmaxf(fmaxf(bx[1], bx[3]), fmaxf(bx[5], bx[7]));
    float s0 = img_sizes[b * 2], s1 = img_sizes[b * 2 + 1];
    float q0 = xmn / s0, q1 = ymn / s1, q2 = xmx / s0, q3 = ymx / s1;

    float tv[2], sv[2];
    float sum = 0.f, sumsq = 0.f;
    #pragma unroll
    for (int i = 0; i < 2; ++i) {
        int d = t + i * 256;
        float v = q0 * Wb[d] + q1 * Wb[512 + d] + q2 * Wb[1024 + d] + q3 * Wb[1536 + d] + bbv[d];
        tv[i] = v; sum += v; sumsq += v * v;
    }
    breduce2(sum, sumsq, red, t);
    float mu = sum * (1.0f / 512.0f);
    float var = sumsq * (1.0f / 512.0f) - mu * mu;
    float rs = rsqrtf(var + 1e-5f);

    sum = 0.f; sumsq = 0.f;
    #pragma unroll
    for (int i = 0; i < 2; ++i) {
        int d = t + i * 256;
        float p = (tv[i] - mu) * rs * g1[d] + be1[d];
        float s = lines[(size_t)row * D_ + d] + p;
        sv[i] = s; sum += s; sumsq += s * s;
    }
    breduce2(sum, sumsq, red, t);
    float mu2 = sum * (1.0f / 512.0f);
    float var2 = sumsq * (1.0f / 512.0f) - mu2 * mu2;
    float rs2 = rsqrtf(var2 + 1e-5f);

    #pragma unroll
    for (int i = 0; i < 2; ++i) {
        int d = t + i * 256;
        float o = (sv[i] - mu2) * rs2 * g2[d] + be2[d];
        out[(size_t)b * (D_ * N_) + (size_t)d * N_ + n] = o;
    }
}

__global__ __launch_bounds__(256) void k_mask(float* __restrict__ out) {
    int i = blockIdx.x * 256 + threadIdx.x;
    if (i < B_ * 32 * 32) out[(size_t)B_ * D_ * N_ + i] = 1.0f;
}

// ---------------------------------------------------------------------------
extern "C" void kernel_launch(void* const* d_in, const int* in_sizes, int n_in,
                              void* d_out, int out_size, void* d_ws, size_t ws_size,
                              hipStream_t stream)
{
    const float* feats = (const float*)d_in[0];
    const float* boxes = (const float*)d_in[1];
    const float* img   = (const float*)d_in[2];
    const float* W1    = (const float*)d_in[3];
    const float* b1    = (const float*)d_in[4];
    const float* W2    = (const float*)d_in[5];
    const float* b2    = (const float*)d_in[6];
    const float* Wb    = (const float*)d_in[7];
    const float* bbv   = (const float*)d_in[8];
    const float* g1    = (const float*)d_in[9];
    const float* be1   = (const float*)d_in[10];
    const float* g2    = (const float*)d_in[11];
    const float* be2   = (const float*)d_in[12];
    float* out = (float*)d_out;
    char* ws = (char*)d_ws;

    // Fast-path ws layout (bytes):
    const size_t OFF_FEATST = 0;                         // bf16 4x65536x256 = 134,217,728
    const size_t OFF_W1T    = 134217728;                 // bf16 512x2304   =   2,359,296
    const size_t OFF_W2T    = 136577024;                 // bf16 512x512    =     524,288
    const size_t OFF_FLAT   = 137101312;                 // bf16 4096x2304  =  18,874,368
    const size_t OFF_ACT    = 155975680;                 // bf16 4096x512   =   4,194,304
    const size_t NEED       = 160169984;

    if (ws_size >= NEED) {
        unsigned short* featsT = (unsigned short*)(ws + OFF_FEATST);
        unsigned short* W1t    = (unsigned short*)(ws + OFF_W1T);
        unsigned short* W2t    = (unsigned short*)(ws + OFF_W2T);
        unsigned short* flat   = (unsigned short*)(ws + OFF_FLAT);
        unsigned short* act    = (unsigned short*)(ws + OFF_ACT);

        // feats (B,CIN,HW) f32 -> featsT (B,HW,CIN) bf16
        k_t64<unsigned short><<<dim3(HW_*HW_/64, CIN_/64, B_), 256, 0, stream>>>(
            feats, featsT, CIN_, HW_*HW_, (size_t)CIN_*HW_*HW_, (size_t)CIN_*HW_*HW_);
        // W1 (2304,512) -> W1t (512,2304) bf16 ; W2 (512,512) -> W2t
        k_t64<unsigned short><<<dim3(D_/64, INK_/64, 1), 256, 0, stream>>>(
            W1, W1t, INK_, D_, 0, 0);
        k_t64<unsigned short><<<dim3(D_/64, D_/64, 1), 256, 0, stream>>>(
            W2, W2t, D_, D_, 0, 0);

        k_roi3<<<BN_/4, 256, 0, stream>>>(featsT, boxes, flat);

        dim3 gg(32, 8);   // M/128 x N/64 = 256 blocks
        k_gemmB<INK_, true><<<gg, 256, 0, stream>>>(flat, W1t, b1, act, nullptr);

        // Fused GEMM2 + LN pipeline + transposed store + mask
        k_fuse2<<<BN_/16, 256, 0, stream>>>(act, W2t, b2, boxes, img,
                                            Wb, bbv, g1, be1, g2, be2, out);
    } else {
        // Fallback: round-1 path (34,340,864 bytes of ws)
        unsigned short* W1t  = (unsigned short*)(ws);
        unsigned short* W2t  = (unsigned short*)(ws + 2359296);
        unsigned short* flat = (unsigned short*)(ws + 2883584);
        unsigned short* act  = (unsigned short*)(ws + 21757952);
        float*          lines= (float*)(ws + 25952256);

        const int convTotal = INK_ * D_ + D_ * D_;
        k_convert<<<(convTotal + 255) / 256, 256, 0, stream>>>(W1, W2, W1t, W2t);
        k_roi<<<BN_, 256, 0, stream>>>(feats, boxes, flat);
        dim3 gg(64, 8);
        k_gemm<INK_, true ><<<gg, 256, 0, stream>>>(flat, W1t, b1, act, nullptr);
        k_gemm<D_,   false><<<gg, 256, 0, stream>>>(act,  W2t, b2, nullptr, lines);
        k_tail<<<BN_, 256, 0, stream>>>(lines, boxes, img, Wb, bbv, g1, be1, g2, be2, out);
        k_mask<<<16, 256, 0, stream>>>(out);
    }
}